// Round 1
// baseline (2972.228 us; speedup 1.0000x reference)
//
#include <hip/hip_runtime.h>
#include <hip/hip_bf16.h>

#ifndef MIN
#define MIN(a,b) ((a)<(b)?(a):(b))
#endif

// ---------------------------------------------------------------------------
// rowdot: fully-unrolled dot of one row (length K) against per-lane weight
// column W[K], with LEAD scalar loads to reach 16B alignment for float4.
// All register-array indices are compile-time constants (no scratch).
// ---------------------------------------------------------------------------
template<int K, int LEAD>
__device__ __forceinline__ void rowdot(const float* __restrict__ row,
                                       const float (&W)[K],
                                       float& a0, float& a1, float& a2, float& a3)
{
#pragma unroll
    for (int k = 0; k < LEAD; ++k) a0 += row[k] * W[k];
    constexpr int NV = (K - LEAD) / 4;
    const float4* v = reinterpret_cast<const float4*>(row + LEAD);
#pragma unroll
    for (int i = 0; i < NV; ++i) {
        float4 x = v[i];
        a0 += x.x * W[LEAD + 4 * i + 0];
        a1 += x.y * W[LEAD + 4 * i + 1];
        a2 += x.z * W[LEAD + 4 * i + 2];
        a3 += x.w * W[LEAD + 4 * i + 3];
    }
#pragma unroll
    for (int k = LEAD + 4 * NV; k < K; ++k) a0 += row[k] * W[k];
}

// ---------------------------------------------------------------------------
// dense64: out[r, c] = (optional relu)( in[r,:] @ (Wa + Wb)[:, c] + ba[c] + bb[c]
//                       + s1[r]*wv1[c] + s2[r]*wv2[c] )
// Wave-per-row; lane c holds weight column c in registers.
// Wb/ba/bb/s1/wv1/s2/wv2 may be nullptr (uniform branches).
// ---------------------------------------------------------------------------
template<int K, bool RELU>
__global__ __launch_bounds__(256)
void dense64(const float* __restrict__ in, int M,
             const float* __restrict__ Wa, const float* __restrict__ Wb,
             const float* __restrict__ ba, const float* __restrict__ bb,
             const float* __restrict__ s1, const float* __restrict__ wv1,
             const float* __restrict__ s2, const float* __restrict__ wv2,
             float* __restrict__ out)
{
    const int lane = threadIdx.x & 63;
    const int gw   = blockIdx.x * (blockDim.x >> 6) + (threadIdx.x >> 6);
    const int nw   = gridDim.x * (blockDim.x >> 6);

    float W[K];
#pragma unroll
    for (int k = 0; k < K; ++k) {
        float w = Wa[k * 64 + lane];
        if (Wb) w += Wb[k * 64 + lane];
        W[k] = w;
    }
    float bias = 0.f;
    if (ba) bias += ba[lane];
    if (bb) bias += bb[lane];
    const float v1 = wv1 ? wv1[lane] : 0.f;
    const float v2 = wv2 ? wv2[lane] : 0.f;

    for (int r = gw; r < M; r += nw) {
        const float* row = in + (size_t)r * K;
        float a0 = 0.f, a1 = 0.f, a2 = 0.f, a3 = 0.f;
        if constexpr ((K & 3) == 0) {
            rowdot<K, 0>(row, W, a0, a1, a2, a3);
        } else {
            switch (r & 3) {
                case 0:  rowdot<K, 0>(row, W, a0, a1, a2, a3); break;
                case 1:  rowdot<K, 3>(row, W, a0, a1, a2, a3); break;
                case 2:  rowdot<K, 2>(row, W, a0, a1, a2, a3); break;
                default: rowdot<K, 1>(row, W, a0, a1, a2, a3); break;
            }
        }
        float acc = bias + (a0 + a1) + (a2 + a3);
        if (s1) acc += s1[r] * v1;
        if (s2) acc += s2[r] * v2;
        if (RELU) acc = fmaxf(acc, 0.f);
        out[(size_t)r * 64 + lane] = acc;
    }
}

// ---------------------------------------------------------------------------
// edge_stage1 (per relation): wave per edge.
//   aggS[dst[e]]        += xsrc[src[e]]            (scalar feature of src node)
//   aggT[src[e], 0..85) += xdst_feat[dst[e], 0..85)
// ---------------------------------------------------------------------------
__global__ __launch_bounds__(256)
void edge_stage1(const float* __restrict__ xsrc,
                 const float* __restrict__ xdst_feat,
                 const int* __restrict__ src, const int* __restrict__ dst, int E,
                 float* __restrict__ aggS, float* __restrict__ aggT)
{
    const int lane = threadIdx.x & 63;
    const int gw   = blockIdx.x * (blockDim.x >> 6) + (threadIdx.x >> 6);
    const int nw   = gridDim.x * (blockDim.x >> 6);
    for (int e = gw; e < E; e += nw) {
        const int s = src[e];
        const int d = dst[e];
        if (lane == 0) atomicAdd(aggS + d, xsrc[s]);
        const float* xr = xdst_feat + (size_t)d * 85;
        float*       ar = aggT + (size_t)s * 85;
        atomicAdd(ar + lane, xr[lane]);
        if (lane < 21) atomicAdd(ar + 64 + lane, xr[64 + lane]);
    }
}

// ---------------------------------------------------------------------------
// edge_scatter64: acc[dst[e], c] += z[src[e], c]  for c in 0..64
// ---------------------------------------------------------------------------
__global__ __launch_bounds__(256)
void edge_scatter64(const float* __restrict__ z,
                    const int* __restrict__ src, const int* __restrict__ dst, int E,
                    float* __restrict__ acc)
{
    const int lane = threadIdx.x & 63;
    const int gw   = blockIdx.x * (blockDim.x >> 6) + (threadIdx.x >> 6);
    const int nw   = gridDim.x * (blockDim.x >> 6);
    for (int e = gw; e < E; e += nw) {
        const int s = src[e];
        const int d = dst[e];
        atomicAdd(acc + (size_t)d * 64 + lane, z[(size_t)s * 64 + lane]);
    }
}

// ---------------------------------------------------------------------------
// final_proj: out[r, 0:2] (+)= relu(tacc[r,:]) @ wlin2[64,2]  (+ blin on INIT)
// Wave per row, shfl reduction.
// ---------------------------------------------------------------------------
template<bool INIT>
__global__ __launch_bounds__(256)
void final_proj(const float* __restrict__ tacc,
                const float* __restrict__ wlin2,
                const float* __restrict__ blin,
                float* __restrict__ out, int M)
{
    const int lane = threadIdx.x & 63;
    const int gw   = blockIdx.x * (blockDim.x >> 6) + (threadIdx.x >> 6);
    const int nw   = gridDim.x * (blockDim.x >> 6);
    const float w0 = wlin2[lane * 2 + 0];
    const float w1 = wlin2[lane * 2 + 1];
    for (int r = gw; r < M; r += nw) {
        const float v = fmaxf(tacc[(size_t)r * 64 + lane], 0.f);
        float a = v * w0;
        float b = v * w1;
        for (int off = 32; off > 0; off >>= 1) {
            a += __shfl_down(a, off);
            b += __shfl_down(b, off);
        }
        if (lane == 0) {
            if (INIT) {
                out[(size_t)r * 2 + 0] = a + blin[0];
                out[(size_t)r * 2 + 1] = b + blin[1];
            } else {
                out[(size_t)r * 2 + 0] += a;
                out[(size_t)r * 2 + 1] += b;
            }
        }
    }
}

// ---------------------------------------------------------------------------
extern "C" void kernel_launch(void* const* d_in, const int* in_sizes, int n_in,
                              void* d_out, int out_size, void* d_ws, size_t ws_size,
                              hipStream_t stream)
{
    const float* x_card   = (const float*)d_in[0];
    const float* x_merch  = (const float*)d_in[1];
    const float* x_trans  = (const float*)d_in[2];
    const float* w1_src_t = (const float*)d_in[3];   // [2,1,64]
    const float* w1_dst_t = (const float*)d_in[4];   // [2,85,64]
    const float* b1_t     = (const float*)d_in[5];   // [2,64]
    const float* w1_src_r = (const float*)d_in[6];   // [2,85,64]
    const float* w1_dst_r = (const float*)d_in[7];   // [2,1,64]
    const float* b1_r     = (const float*)d_in[8];   // [2,64]
    const float* w2_l     = (const float*)d_in[9];   // [4,64,64]
    const float* w2_r     = (const float*)d_in[10];  // [4,64,64]
    const float* b2       = (const float*)d_in[11];  // [4,64]
    const float* w_lin    = (const float*)d_in[12];  // [128,2]
    const float* b_lin    = (const float*)d_in[13];  // [2]
    const int*   src_pays = (const int*)d_in[14];
    const int*   dst_pays = (const int*)d_in[15];
    const int*   src_recv = (const int*)d_in[16];
    const int*   dst_recv = (const int*)d_in[17];
    float*       out      = (float*)d_out;

    const int Nc = in_sizes[0];
    const int Nm = in_sizes[1];
    const int Nt = in_sizes[2] / 85;
    const int E  = in_sizes[14];

    // workspace layout
    char* wsp = (char*)d_ws;
    auto alloc = [&](size_t bytes) -> float* {
        char* p = wsp;
        wsp += (bytes + 255) & ~(size_t)255;
        return (float*)p;
    };
    float* agg_c  = alloc((size_t)Nt * 4);          // scalar card agg per transaction
    float* agg_m  = alloc((size_t)Nt * 4);          // scalar merchant agg per transaction
    float* aggT_c = alloc((size_t)Nc * 85 * 4);     // summed transaction feats per card
    float* aggT_m = alloc((size_t)Nm * 85 * 4);     // summed transaction feats per merchant
    const size_t zero_bytes = (size_t)(wsp - (char*)d_ws);
    float* h_t  = alloc((size_t)Nt * 64 * 4);
    float* h_c  = alloc((size_t)Nc * 64 * 4);
    float* h_m  = alloc((size_t)Nm * 64 * 4);
    float* z1   = alloc((size_t)Nc * 64 * 4);
    float* z2   = alloc((size_t)Nm * 64 * 4);
    float* tacc = alloc((size_t)Nt * 64 * 4);
    (void)ws_size; (void)n_in; (void)out_size;

    hipMemsetAsync(d_ws, 0, zero_bytes, stream);

    const dim3 blk(256);
    const int gEdge  = MIN((E + 3) / 4, 2048);
    const int gBig   = MIN((Nt + 3) / 4, 2048);
    const int gCard  = MIN((Nc + 3) / 4, 2048);
    const int gMerch = MIN((Nm + 3) / 4, 2048);

    // Stage A: edge aggregations for conv1
    edge_stage1<<<gEdge, blk, 0, stream>>>(x_card,  x_trans, src_pays, dst_pays, E, agg_c, aggT_c);
    edge_stage1<<<gEdge, blk, 0, stream>>>(x_merch, x_trans, src_recv, dst_recv, E, agg_m, aggT_m);

    // Stage B: conv1 dense transforms (+relu)
    dense64<85, true><<<gBig, blk, 0, stream>>>(
        x_trans, Nt, w1_dst_t, w1_dst_t + 85 * 64, b1_t, b1_t + 64,
        agg_c, w1_src_t, agg_m, w1_src_t + 64, h_t);
    dense64<85, true><<<gCard, blk, 0, stream>>>(
        aggT_c, Nc, w1_src_r, nullptr, b1_r, nullptr,
        x_card, w1_dst_r, nullptr, nullptr, h_c);
    dense64<85, true><<<gMerch, blk, 0, stream>>>(
        aggT_m, Nm, w1_src_r + 85 * 64, nullptr, b1_r + 64, nullptr,
        x_merch, w1_dst_r + 64, nullptr, nullptr, h_m);

    // Stage C: pre-transform small node sets for conv2 (linearity trick)
    dense64<64, false><<<gCard, blk, 0, stream>>>(
        h_c, Nc, w2_l, nullptr, nullptr, nullptr,
        nullptr, nullptr, nullptr, nullptr, z1);
    dense64<64, false><<<gMerch, blk, 0, stream>>>(
        h_m, Nm, w2_l + 64 * 64, nullptr, nullptr, nullptr,
        nullptr, nullptr, nullptr, nullptr, z2);

    // Relation 0 (pays): tacc = h_t @ w2_r[0] + b2[0]; scatter z1; project
    dense64<64, false><<<gBig, blk, 0, stream>>>(
        h_t, Nt, w2_r, nullptr, b2, nullptr,
        nullptr, nullptr, nullptr, nullptr, tacc);
    edge_scatter64<<<gEdge, blk, 0, stream>>>(z1, src_pays, dst_pays, E, tacc);
    final_proj<true><<<gBig, blk, 0, stream>>>(tacc, w_lin, b_lin, out, Nt);

    // Relation 1 (receives): reuse tacc
    dense64<64, false><<<gBig, blk, 0, stream>>>(
        h_t, Nt, w2_r + 64 * 64, nullptr, b2 + 64, nullptr,
        nullptr, nullptr, nullptr, nullptr, tacc);
    edge_scatter64<<<gEdge, blk, 0, stream>>>(z2, src_recv, dst_recv, E, tacc);
    final_proj<false><<<gBig, blk, 0, stream>>>(tacc, w_lin + 128, b_lin, out, Nt);
}

// Round 2
// 1529.393 us; speedup vs baseline: 1.9434x; 1.9434x over previous
//
#include <hip/hip_runtime.h>
#include <hip/hip_bf16.h>

#ifndef MIN
#define MIN(a,b) ((a)<(b)?(a):(b))
#endif

// ---------------------------------------------------------------------------
// rowdot: fully-unrolled dot of one row (length K, 16B-aligned) against
// per-lane weight column W[K]. Row pointer may be LDS (broadcast reads).
// ---------------------------------------------------------------------------
template<int K>
__device__ __forceinline__ void rowdot(const float* __restrict__ row,
                                       const float (&W)[K],
                                       float& a0, float& a1, float& a2, float& a3)
{
    constexpr int NV = K / 4;
    const float4* v = reinterpret_cast<const float4*>(row);
#pragma unroll
    for (int i = 0; i < NV; ++i) {
        float4 x = v[i];
        a0 += x.x * W[4 * i + 0];
        a1 += x.y * W[4 * i + 1];
        a2 += x.z * W[4 * i + 2];
        a3 += x.w * W[4 * i + 3];
    }
#pragma unroll
    for (int k = 4 * NV; k < K; ++k) a0 += row[k] * W[k];
}

// ---------------------------------------------------------------------------
// dense64t: out[r, c] = (optional relu)( in[r,:] @ (Wa + Wb)[:, c] + ba[c]
//              + bb[c] + s1[r]*wv1[c] + s2[r]*wv2[c] )
// Tiled: 64 rows staged into LDS with coalesced float4 loads; 4 waves per
// block each compute 16 rows (lane = output column, weights in VGPRs).
// KP = LDS row pitch in floats (multiple of 4 so every LDS row is 16B-aligned).
// ---------------------------------------------------------------------------
template<int K, int KP, bool RELU>
__global__ __launch_bounds__(256)
void dense64t(const float* __restrict__ in, int M,
              const float* __restrict__ Wa, const float* __restrict__ Wb,
              const float* __restrict__ ba, const float* __restrict__ bb,
              const float* __restrict__ s1, const float* __restrict__ wv1,
              const float* __restrict__ s2, const float* __restrict__ wv2,
              float* __restrict__ out)
{
    constexpr int R = 64;                 // rows per tile
    __shared__ float buf[R * KP];
    __shared__ float sbuf[2][R];
    const int tid  = threadIdx.x;
    const int lane = tid & 63;
    const int wid  = tid >> 6;

    float W[K];
#pragma unroll
    for (int k = 0; k < K; ++k) {
        float w = Wa[k * 64 + lane];
        if (Wb) w += Wb[k * 64 + lane];
        W[k] = w;
    }
    float bias = 0.f;
    if (ba) bias += ba[lane];
    if (bb) bias += bb[lane];
    const float v1 = wv1 ? wv1[lane] : 0.f;
    const float v2 = wv2 ? wv2[lane] : 0.f;

    const int ntiles = (M + R - 1) / R;
    for (int t = blockIdx.x; t < ntiles; t += gridDim.x) {
        const int base = t * R;
        const int rows = MIN(R, M - base);
        __syncthreads();                  // protect buf from previous iter
        // ---- stage tile (the 64-row slab is contiguous in row-major in) ----
        const int nf = rows * K;
        if constexpr (K == KP) {
            const float4* src4 = reinterpret_cast<const float4*>(in + (size_t)base * K);
            for (int i = tid; i < nf / 4; i += 256)
                reinterpret_cast<float4*>(buf)[i] = src4[i];
        } else {
            // base*K*4 bytes is 16B-aligned: base is a multiple of 64 and
            // 64*K*4 % 16 == 0 for any K.
            const float*  src  = in + (size_t)base * K;
            const float4* src4 = reinterpret_cast<const float4*>(src);
            const int nv = nf / 4;
            for (int i = tid; i < nv; i += 256) {
                float4 v = src4[i];
                const int e = i * 4;
#pragma unroll
                for (int j = 0; j < 4; ++j) {
                    const int ee = e + j;
                    const int r  = ee / K;
                    const int c  = ee - r * K;
                    buf[r * KP + c] = (&v.x)[j];
                }
            }
            for (int i = nv * 4 + tid; i < nf; i += 256) {
                const int r = i / K;
                const int c = i - r * K;
                buf[r * KP + c] = src[i];
            }
        }
        if (s1 && tid < rows) sbuf[0][tid] = s1[base + tid];
        if (s2 && tid >= 64 && tid < 64 + rows) sbuf[1][tid - 64] = s2[base + tid - 64];
        __syncthreads();
        // ---- compute: wave wid owns rows [wid*16, wid*16+16) ----
        const int r0 = wid * (R / 4);
#pragma unroll 1
        for (int rr = 0; rr < R / 4; ++rr) {
            const int r = r0 + rr;
            if (r >= rows) break;
            const float* row = &buf[r * KP];
            float a0 = 0.f, a1 = 0.f, a2 = 0.f, a3 = 0.f;
            rowdot<K>(row, W, a0, a1, a2, a3);
            float acc = bias + (a0 + a1) + (a2 + a3);
            if (s1) acc += sbuf[0][r] * v1;
            if (s2) acc += sbuf[1][r] * v2;
            if (RELU) acc = fmaxf(acc, 0.f);
            out[(size_t)(base + r) * 64 + lane] = acc;
        }
    }
}

// ---------------------------------------------------------------------------
// edge_stage1 (per relation): wave per edge.
//   aggS[dst[e]]        += xsrc[src[e]]            (scalar feature of src node)
//   aggT[src[e], 0..85) += xdst_feat[dst[e], 0..85)
// ---------------------------------------------------------------------------
__global__ __launch_bounds__(256)
void edge_stage1(const float* __restrict__ xsrc,
                 const float* __restrict__ xdst_feat,
                 const int* __restrict__ src, const int* __restrict__ dst, int E,
                 float* __restrict__ aggS, float* __restrict__ aggT)
{
    const int lane = threadIdx.x & 63;
    const int gw   = blockIdx.x * (blockDim.x >> 6) + (threadIdx.x >> 6);
    const int nw   = gridDim.x * (blockDim.x >> 6);
    for (int e = gw; e < E; e += nw) {
        const int s = src[e];
        const int d = dst[e];
        if (lane == 0) atomicAdd(aggS + d, xsrc[s]);
        const float* xr = xdst_feat + (size_t)d * 85;
        float*       ar = aggT + (size_t)s * 85;
        atomicAdd(ar + lane, xr[lane]);
        if (lane < 21) atomicAdd(ar + 64 + lane, xr[64 + lane]);
    }
}

// ---------------------------------------------------------------------------
// edge_scatter64: acc[dst[e], c] += z[src[e], c]  for c in 0..64
// ---------------------------------------------------------------------------
__global__ __launch_bounds__(256)
void edge_scatter64(const float* __restrict__ z,
                    const int* __restrict__ src, const int* __restrict__ dst, int E,
                    float* __restrict__ acc)
{
    const int lane = threadIdx.x & 63;
    const int gw   = blockIdx.x * (blockDim.x >> 6) + (threadIdx.x >> 6);
    const int nw   = gridDim.x * (blockDim.x >> 6);
    for (int e = gw; e < E; e += nw) {
        const int s = src[e];
        const int d = dst[e];
        atomicAdd(acc + (size_t)d * 64 + lane, z[(size_t)s * 64 + lane]);
    }
}

// ---------------------------------------------------------------------------
// final_proj: out[r, 0:2] (+)= relu(tacc[r,:]) @ wlin2[64,2]  (+ blin on INIT)
// ---------------------------------------------------------------------------
template<bool INIT>
__global__ __launch_bounds__(256)
void final_proj(const float* __restrict__ tacc,
                const float* __restrict__ wlin2,
                const float* __restrict__ blin,
                float* __restrict__ out, int M)
{
    const int lane = threadIdx.x & 63;
    const int gw   = blockIdx.x * (blockDim.x >> 6) + (threadIdx.x >> 6);
    const int nw   = gridDim.x * (blockDim.x >> 6);
    const float w0 = wlin2[lane * 2 + 0];
    const float w1 = wlin2[lane * 2 + 1];
    for (int r = gw; r < M; r += nw) {
        const float v = fmaxf(tacc[(size_t)r * 64 + lane], 0.f);
        float a = v * w0;
        float b = v * w1;
        for (int off = 32; off > 0; off >>= 1) {
            a += __shfl_down(a, off);
            b += __shfl_down(b, off);
        }
        if (lane == 0) {
            if (INIT) {
                out[(size_t)r * 2 + 0] = a + blin[0];
                out[(size_t)r * 2 + 1] = b + blin[1];
            } else {
                out[(size_t)r * 2 + 0] += a;
                out[(size_t)r * 2 + 1] += b;
            }
        }
    }
}

// ---------------------------------------------------------------------------
extern "C" void kernel_launch(void* const* d_in, const int* in_sizes, int n_in,
                              void* d_out, int out_size, void* d_ws, size_t ws_size,
                              hipStream_t stream)
{
    const float* x_card   = (const float*)d_in[0];
    const float* x_merch  = (const float*)d_in[1];
    const float* x_trans  = (const float*)d_in[2];
    const float* w1_src_t = (const float*)d_in[3];   // [2,1,64]
    const float* w1_dst_t = (const float*)d_in[4];   // [2,85,64]
    const float* b1_t     = (const float*)d_in[5];   // [2,64]
    const float* w1_src_r = (const float*)d_in[6];   // [2,85,64]
    const float* w1_dst_r = (const float*)d_in[7];   // [2,1,64]
    const float* b1_r     = (const float*)d_in[8];   // [2,64]
    const float* w2_l     = (const float*)d_in[9];   // [4,64,64]
    const float* w2_r     = (const float*)d_in[10];  // [4,64,64]
    const float* b2       = (const float*)d_in[11];  // [4,64]
    const float* w_lin    = (const float*)d_in[12];  // [128,2]
    const float* b_lin    = (const float*)d_in[13];  // [2]
    const int*   src_pays = (const int*)d_in[14];
    const int*   dst_pays = (const int*)d_in[15];
    const int*   src_recv = (const int*)d_in[16];
    const int*   dst_recv = (const int*)d_in[17];
    float*       out      = (float*)d_out;

    const int Nc = in_sizes[0];
    const int Nm = in_sizes[1];
    const int Nt = in_sizes[2] / 85;
    const int E  = in_sizes[14];

    // workspace layout
    char* wsp = (char*)d_ws;
    auto alloc = [&](size_t bytes) -> float* {
        char* p = wsp;
        wsp += (bytes + 255) & ~(size_t)255;
        return (float*)p;
    };
    float* agg_c  = alloc((size_t)Nt * 4);
    float* agg_m  = alloc((size_t)Nt * 4);
    float* aggT_c = alloc((size_t)Nc * 85 * 4);
    float* aggT_m = alloc((size_t)Nm * 85 * 4);
    const size_t zero_bytes = (size_t)(wsp - (char*)d_ws);
    float* h_t  = alloc((size_t)Nt * 64 * 4);
    float* h_c  = alloc((size_t)Nc * 64 * 4);
    float* h_m  = alloc((size_t)Nm * 64 * 4);
    float* z1   = alloc((size_t)Nc * 64 * 4);
    float* z2   = alloc((size_t)Nm * 64 * 4);
    float* tacc = alloc((size_t)Nt * 64 * 4);
    (void)ws_size; (void)n_in; (void)out_size;

    hipMemsetAsync(d_ws, 0, zero_bytes, stream);

    const dim3 blk(256);
    const int gEdge  = MIN((E + 3) / 4, 2048);
    const int gBig   = MIN((Nt + 3) / 4, 2048);
    auto tiles = [](int M) { return (M + 63) / 64; };

    // Stage A: edge aggregations for conv1
    edge_stage1<<<gEdge, blk, 0, stream>>>(x_card,  x_trans, src_pays, dst_pays, E, agg_c, aggT_c);
    edge_stage1<<<gEdge, blk, 0, stream>>>(x_merch, x_trans, src_recv, dst_recv, E, agg_m, aggT_m);

    // Stage B: conv1 dense transforms (+relu)
    dense64t<85, 88, true><<<tiles(Nt), blk, 0, stream>>>(
        x_trans, Nt, w1_dst_t, w1_dst_t + 85 * 64, b1_t, b1_t + 64,
        agg_c, w1_src_t, agg_m, w1_src_t + 64, h_t);
    dense64t<85, 88, true><<<tiles(Nc), blk, 0, stream>>>(
        aggT_c, Nc, w1_src_r, nullptr, b1_r, nullptr,
        x_card, w1_dst_r, nullptr, nullptr, h_c);
    dense64t<85, 88, true><<<tiles(Nm), blk, 0, stream>>>(
        aggT_m, Nm, w1_src_r + 85 * 64, nullptr, b1_r + 64, nullptr,
        x_merch, w1_dst_r + 64, nullptr, nullptr, h_m);

    // Stage C: pre-transform small node sets for conv2 (linearity trick)
    dense64t<64, 64, false><<<tiles(Nc), blk, 0, stream>>>(
        h_c, Nc, w2_l, nullptr, nullptr, nullptr,
        nullptr, nullptr, nullptr, nullptr, z1);
    dense64t<64, 64, false><<<tiles(Nm), blk, 0, stream>>>(
        h_m, Nm, w2_l + 64 * 64, nullptr, nullptr, nullptr,
        nullptr, nullptr, nullptr, nullptr, z2);

    // Relation 0 (pays): tacc = h_t @ w2_r[0] + b2[0]; scatter z1; project
    dense64t<64, 64, false><<<tiles(Nt), blk, 0, stream>>>(
        h_t, Nt, w2_r, nullptr, b2, nullptr,
        nullptr, nullptr, nullptr, nullptr, tacc);
    edge_scatter64<<<gEdge, blk, 0, stream>>>(z1, src_pays, dst_pays, E, tacc);
    final_proj<true><<<gBig, blk, 0, stream>>>(tacc, w_lin, b_lin, out, Nt);

    // Relation 1 (receives): reuse tacc
    dense64t<64, 64, false><<<tiles(Nt), blk, 0, stream>>>(
        h_t, Nt, w2_r + 64 * 64, nullptr, b2 + 64, nullptr,
        nullptr, nullptr, nullptr, nullptr, tacc);
    edge_scatter64<<<gEdge, blk, 0, stream>>>(z2, src_recv, dst_recv, E, tacc);
    final_proj<false><<<gBig, blk, 0, stream>>>(tacc, w_lin + 128, b_lin, out, Nt);
}

// Round 3
// 993.196 us; speedup vs baseline: 2.9926x; 1.5399x over previous
//
#include <hip/hip_runtime.h>
#include <hip/hip_bf16.h>

#ifndef MIN
#define MIN(a,b) ((a)<(b)?(a):(b))
#endif

#define RFL(x) __builtin_amdgcn_readfirstlane(x)

// ---------------------------------------------------------------------------
// fused_sage85: per 64-row tile of `in` [M][85]:
//   h[r][c]   = relu( in[r,:]@Wsum[:,c] + bsum[c] + s1[r]*wv1[c] (+ s2[r]*wv2[c]) )
//   outR[r][c]= h[r,:]@W2[R][:,c] (+ b2v[R][c])        for R < NREL
// lane = row (conflict-free LDS, pitch 85 / 65), wave = 16-col slice,
// weights via wave-uniform scalar loads (readfirstlane'd column base).
// ---------------------------------------------------------------------------
template<int NREL, bool HAS_S2, bool HAS_B2>
__global__ __launch_bounds__(256)
void fused_sage85(const float* __restrict__ in, int M,
                  const float* __restrict__ Wsum,   // [85][64]
                  const float* __restrict__ bsum,   // [64]
                  const float* __restrict__ s1, const float* __restrict__ wv1,
                  const float* __restrict__ s2, const float* __restrict__ wv2,
                  const float* __restrict__ W2,     // [NREL][64][64]
                  const float* __restrict__ b2v,    // [NREL][64]
                  float* __restrict__ out0, float* __restrict__ out1)
{
    constexpr int K = 85;
    __shared__ float xbuf[64 * K];     // packed rows, pitch 85 (21≡ mod 32, free)
    __shared__ float hbuf[64 * 65];    // pitch 65 (stride≡1 mod 32, free)
    const int tid  = threadIdx.x;
    const int lane = tid & 63;
    const int wid  = tid >> 6;
    const int c0   = RFL(wid * 16);    // wave-uniform column base -> s_loads

    const int ntiles = (M + 63) >> 6;
    for (int t = blockIdx.x; t < ntiles; t += gridDim.x) {
        const int base = t << 6;
        const int rows = MIN(64, M - base);
        __syncthreads();               // xbuf/hbuf free from previous tile
        // ---- stage: linear copy (64-row slab is contiguous; 16B aligned) ----
        {
            const int nw = rows * K;
            const float4* s4 = reinterpret_cast<const float4*>(in + (size_t)base * K);
            const int nv = nw >> 2;
            for (int i = tid; i < nv; i += 256)
                reinterpret_cast<float4*>(xbuf)[i] = s4[i];
            for (int i = (nv << 2) + tid; i < nw; i += 256)
                xbuf[i] = in[(size_t)base * K + i];
        }
        __syncthreads();
        // ---- phase 1: h-row slice in registers ----
        float acc[16];
#pragma unroll
        for (int j = 0; j < 16; ++j) acc[j] = bsum[c0 + j];
        {
            const float sv1 = (lane < rows) ? s1[base + lane] : 0.f;
#pragma unroll
            for (int j = 0; j < 16; ++j) acc[j] = fmaf(sv1, wv1[c0 + j], acc[j]);
        }
        if constexpr (HAS_S2) {
            const float sv2 = (lane < rows) ? s2[base + lane] : 0.f;
#pragma unroll
            for (int j = 0; j < 16; ++j) acc[j] = fmaf(sv2, wv2[c0 + j], acc[j]);
        }
        {
            const float* xr = xbuf + lane * K;
#pragma unroll 5
            for (int k = 0; k < K; ++k) {
                const float xk = xr[k];
                const float* wk = Wsum + k * 64 + c0;
#pragma unroll
                for (int j = 0; j < 16; ++j) acc[j] = fmaf(xk, wk[j], acc[j]);
            }
        }
#pragma unroll
        for (int j = 0; j < 16; ++j) hbuf[lane * 65 + c0 + j] = fmaxf(acc[j], 0.f);
        __syncthreads();
        // ---- phase 2: second GEMM(s), h from LDS ----
        float a2[NREL][16];
#pragma unroll
        for (int rel = 0; rel < NREL; ++rel)
#pragma unroll
            for (int j = 0; j < 16; ++j)
                a2[rel][j] = HAS_B2 ? b2v[rel * 64 + c0 + j] : 0.f;
        {
            const float* hr = hbuf + lane * 65;
#pragma unroll 4
            for (int k = 0; k < 64; ++k) {
                const float hk = hr[k];
#pragma unroll
                for (int rel = 0; rel < NREL; ++rel) {
                    const float* wk = W2 + rel * 4096 + k * 64 + c0;
#pragma unroll
                    for (int j = 0; j < 16; ++j)
                        a2[rel][j] = fmaf(hk, wk[j], a2[rel][j]);
                }
            }
        }
        if (lane < rows) {
            float* o0 = out0 + (size_t)(base + lane) * 64 + c0;
#pragma unroll
            for (int j4 = 0; j4 < 4; ++j4)
                reinterpret_cast<float4*>(o0)[j4] =
                    make_float4(a2[0][4*j4], a2[0][4*j4+1], a2[0][4*j4+2], a2[0][4*j4+3]);
            if constexpr (NREL == 2) {
                float* o1 = out1 + (size_t)(base + lane) * 64 + c0;
#pragma unroll
                for (int j4 = 0; j4 < 4; ++j4)
                    reinterpret_cast<float4*>(o1)[j4] =
                        make_float4(a2[1][4*j4], a2[1][4*j4+1], a2[1][4*j4+2], a2[1][4*j4+3]);
            }
        }
    }
}

// ---------------------------------------------------------------------------
// prep: Wsum = w1_dst_t[0] + w1_dst_t[1]; bsum = b1_t[0] + b1_t[1]
// ---------------------------------------------------------------------------
__global__ __launch_bounds__(256)
void prep(const float* __restrict__ w1dt, const float* __restrict__ b1t,
          float* __restrict__ wsum, float* __restrict__ bsum)
{
    const int i = blockIdx.x * 256 + threadIdx.x;
    if (i < 85 * 64) wsum[i] = w1dt[i] + w1dt[85 * 64 + i];
    if (i < 64)      bsum[i] = b1t[i] + b1t[64 + i];
}

// ---------------------------------------------------------------------------
// edge_stage1 (per relation): wave per edge.
// ---------------------------------------------------------------------------
__global__ __launch_bounds__(256)
void edge_stage1(const float* __restrict__ xsrc,
                 const float* __restrict__ xdst_feat,
                 const int* __restrict__ src, const int* __restrict__ dst, int E,
                 float* __restrict__ aggS, float* __restrict__ aggT)
{
    const int lane = threadIdx.x & 63;
    const int gw   = blockIdx.x * (blockDim.x >> 6) + (threadIdx.x >> 6);
    const int nw   = gridDim.x * (blockDim.x >> 6);
    for (int e = gw; e < E; e += nw) {
        const int s = src[e];
        const int d = dst[e];
        if (lane == 0) atomicAdd(aggS + d, xsrc[s]);
        const float* xr = xdst_feat + (size_t)d * 85;
        float*       ar = aggT + (size_t)s * 85;
        atomicAdd(ar + lane, xr[lane]);
        if (lane < 21) atomicAdd(ar + 64 + lane, xr[64 + lane]);
    }
}

// ---------------------------------------------------------------------------
// edge_scatter64: acc[dst[e], c] += z[src[e], c]
// ---------------------------------------------------------------------------
__global__ __launch_bounds__(256)
void edge_scatter64(const float* __restrict__ z,
                    const int* __restrict__ src, const int* __restrict__ dst, int E,
                    float* __restrict__ acc)
{
    const int lane = threadIdx.x & 63;
    const int gw   = blockIdx.x * (blockDim.x >> 6) + (threadIdx.x >> 6);
    const int nw   = gridDim.x * (blockDim.x >> 6);
    for (int e = gw; e < E; e += nw) {
        const int s = src[e];
        const int d = dst[e];
        atomicAdd(acc + (size_t)d * 64 + lane, z[(size_t)s * 64 + lane]);
    }
}

// ---------------------------------------------------------------------------
// final2: out[r][o] = blin[o] + sum_c relu(t0[r][c])*wl[c][o]
//                            + sum_c relu(t1[r][c])*wl[64+c][o]
// 4 lanes per row (coalesced 64B groups), shfl_xor reduce.
// ---------------------------------------------------------------------------
__global__ __launch_bounds__(256)
void final2(const float* __restrict__ t0, const float* __restrict__ t1,
            const float* __restrict__ wl, const float* __restrict__ bl,
            float* __restrict__ out, int M)
{
    const int lane = threadIdx.x & 63;
    const int p    = lane & 3;
    const int rsub = lane >> 2;
    const int gw   = blockIdx.x * (blockDim.x >> 6) + (threadIdx.x >> 6);
    const int nw   = gridDim.x * (blockDim.x >> 6);
    float w00[16], w01[16], w10[16], w11[16];
#pragma unroll
    for (int i = 0; i < 4; ++i)
#pragma unroll
        for (int q = 0; q < 4; ++q) {
            const int c = (p + 4 * i) * 4 + q;
            w00[i*4+q] = wl[c*2+0];        w01[i*4+q] = wl[c*2+1];
            w10[i*4+q] = wl[(64+c)*2+0];   w11[i*4+q] = wl[(64+c)*2+1];
        }
    const float b0 = bl[0], b1 = bl[1];
    const int ngrp = (M + 15) >> 4;
    for (int g = gw; g < ngrp; g += nw) {
        const int r = (g << 4) + rsub;
        if (r >= M) continue;
        const float4* r0 = reinterpret_cast<const float4*>(t0 + (size_t)r * 64);
        const float4* r1 = reinterpret_cast<const float4*>(t1 + (size_t)r * 64);
        float a0 = 0.f, a1 = 0.f;
#pragma unroll
        for (int i = 0; i < 4; ++i) {
            const float4 v = r0[p + 4 * i];
            const float x0 = fmaxf(v.x,0.f), x1 = fmaxf(v.y,0.f),
                        x2 = fmaxf(v.z,0.f), x3 = fmaxf(v.w,0.f);
            a0 += x0*w00[i*4+0] + x1*w00[i*4+1] + x2*w00[i*4+2] + x3*w00[i*4+3];
            a1 += x0*w01[i*4+0] + x1*w01[i*4+1] + x2*w01[i*4+2] + x3*w01[i*4+3];
        }
#pragma unroll
        for (int i = 0; i < 4; ++i) {
            const float4 v = r1[p + 4 * i];
            const float x0 = fmaxf(v.x,0.f), x1 = fmaxf(v.y,0.f),
                        x2 = fmaxf(v.z,0.f), x3 = fmaxf(v.w,0.f);
            a0 += x0*w10[i*4+0] + x1*w10[i*4+1] + x2*w10[i*4+2] + x3*w10[i*4+3];
            a1 += x0*w11[i*4+0] + x1*w11[i*4+1] + x2*w11[i*4+2] + x3*w11[i*4+3];
        }
        a0 += __shfl_xor(a0, 1); a0 += __shfl_xor(a0, 2);
        a1 += __shfl_xor(a1, 1); a1 += __shfl_xor(a1, 2);
        if (p == 0) {
            out[(size_t)r * 2 + 0] = a0 + b0;
            out[(size_t)r * 2 + 1] = a1 + b1;
        }
    }
}

// ---------------------------------------------------------------------------
extern "C" void kernel_launch(void* const* d_in, const int* in_sizes, int n_in,
                              void* d_out, int out_size, void* d_ws, size_t ws_size,
                              hipStream_t stream)
{
    const float* x_card   = (const float*)d_in[0];
    const float* x_merch  = (const float*)d_in[1];
    const float* x_trans  = (const float*)d_in[2];
    const float* w1_src_t = (const float*)d_in[3];   // [2,1,64]
    const float* w1_dst_t = (const float*)d_in[4];   // [2,85,64]
    const float* b1_t     = (const float*)d_in[5];   // [2,64]
    const float* w1_src_r = (const float*)d_in[6];   // [2,85,64]
    const float* w1_dst_r = (const float*)d_in[7];   // [2,1,64]
    const float* b1_r     = (const float*)d_in[8];   // [2,64]
    const float* w2_l     = (const float*)d_in[9];   // [4,64,64]
    const float* w2_r     = (const float*)d_in[10];  // [4,64,64]
    const float* b2       = (const float*)d_in[11];  // [4,64]
    const float* w_lin    = (const float*)d_in[12];  // [128,2]
    const float* b_lin    = (const float*)d_in[13];  // [2]
    const int*   src_pays = (const int*)d_in[14];
    const int*   dst_pays = (const int*)d_in[15];
    const int*   src_recv = (const int*)d_in[16];
    const int*   dst_recv = (const int*)d_in[17];
    float*       out      = (float*)d_out;

    const int Nc = in_sizes[0];
    const int Nm = in_sizes[1];
    const int Nt = in_sizes[2] / 85;
    const int E  = in_sizes[14];

    // workspace layout
    char* wsp = (char*)d_ws;
    auto alloc = [&](size_t bytes) -> float* {
        char* p = wsp;
        wsp += (bytes + 255) & ~(size_t)255;
        return (float*)p;
    };
    float* agg_c  = alloc((size_t)Nt * 4);
    float* agg_m  = alloc((size_t)Nt * 4);
    float* aggT_c = alloc((size_t)Nc * 85 * 4);
    float* aggT_m = alloc((size_t)Nm * 85 * 4);
    const size_t zero_bytes = (size_t)(wsp - (char*)d_ws);
    float* wsum  = alloc((size_t)85 * 64 * 4);
    float* bsum  = alloc((size_t)64 * 4);
    float* z1    = alloc((size_t)Nc * 64 * 4);
    float* z2    = alloc((size_t)Nm * 64 * 4);
    float* tacc0 = alloc((size_t)Nt * 64 * 4);
    float* tacc1 = alloc((size_t)Nt * 64 * 4);
    (void)ws_size; (void)n_in; (void)out_size;

    hipMemsetAsync(d_ws, 0, zero_bytes, stream);

    const dim3 blk(256);
    const int gEdge = MIN((E + 3) / 4, 2048);
    auto tiles = [](int M) { return (M + 63) / 64; };

    // weight precompute (independent of edge kernels)
    prep<<<(85 * 64 + 255) / 256, blk, 0, stream>>>(w1_dst_t, b1_t, wsum, bsum);

    // Stage A: edge aggregations for conv1
    edge_stage1<<<gEdge, blk, 0, stream>>>(x_card,  x_trans, src_pays, dst_pays, E, agg_c, aggT_c);
    edge_stage1<<<gEdge, blk, 0, stream>>>(x_merch, x_trans, src_recv, dst_recv, E, agg_m, aggT_m);

    // megaT: x_trans -> h_t (in-reg) -> tacc0, tacc1
    fused_sage85<2, true, true><<<tiles(Nt), blk, 0, stream>>>(
        x_trans, Nt, wsum, bsum,
        agg_c, w1_src_t, agg_m, w1_src_t + 64,
        w2_r, b2, tacc0, tacc1);

    // megaC: aggT_c -> h_c (in-reg) -> z1 = h_c @ w2_l[0]
    fused_sage85<1, false, false><<<tiles(Nc), blk, 0, stream>>>(
        aggT_c, Nc, w1_src_r, b1_r,
        x_card, w1_dst_r, nullptr, nullptr,
        w2_l, nullptr, z1, nullptr);

    // megaM: aggT_m -> h_m (in-reg) -> z2 = h_m @ w2_l[1]
    fused_sage85<1, false, false><<<tiles(Nm), blk, 0, stream>>>(
        aggT_m, Nm, w1_src_r + 85 * 64, b1_r + 64,
        x_merch, w1_dst_r + 64, nullptr, nullptr,
        w2_l + 64 * 64, nullptr, z2, nullptr);

    // conv2 neighbor terms: scatter z rows into tacc
    edge_scatter64<<<gEdge, blk, 0, stream>>>(z1, src_pays, dst_pays, E, tacc0);
    edge_scatter64<<<gEdge, blk, 0, stream>>>(z2, src_recv, dst_recv, E, tacc1);

    // final projection
    final2<<<2048, blk, 0, stream>>>(tacc0, tacc1, w_lin, b_lin, out, Nt);
}

// Round 4
// 948.076 us; speedup vs baseline: 3.1350x; 1.0476x over previous
//
#include <hip/hip_runtime.h>
#include <hip/hip_bf16.h>

#ifndef MIN
#define MIN(a,b) ((a)<(b)?(a):(b))
#endif

#define RFL(x) __builtin_amdgcn_readfirstlane(x)

// ---------------------------------------------------------------------------
// fused_sage85 (unchanged from R3): per 64-row tile of `in` [M][85]:
//   h[r][c]   = relu( in[r,:]@Wsum[:,c] + bsum[c] + s1[r]*wv1[c] (+ s2[r]*wv2[c]) )
//   outR[r][c]= h[r,:]@W2[R][:,c] (+ b2v[R][c])
// ---------------------------------------------------------------------------
template<int NREL, bool HAS_S2, bool HAS_B2>
__global__ __launch_bounds__(256)
void fused_sage85(const float* __restrict__ in, int M,
                  const float* __restrict__ Wsum,
                  const float* __restrict__ bsum,
                  const float* __restrict__ s1, const float* __restrict__ wv1,
                  const float* __restrict__ s2, const float* __restrict__ wv2,
                  const float* __restrict__ W2,
                  const float* __restrict__ b2v,
                  float* __restrict__ out0, float* __restrict__ out1)
{
    constexpr int K = 85;
    __shared__ float xbuf[64 * K];
    __shared__ float hbuf[64 * 65];
    const int tid  = threadIdx.x;
    const int lane = tid & 63;
    const int wid  = tid >> 6;
    const int c0   = RFL(wid * 16);

    const int ntiles = (M + 63) >> 6;
    for (int t = blockIdx.x; t < ntiles; t += gridDim.x) {
        const int base = t << 6;
        const int rows = MIN(64, M - base);
        __syncthreads();
        {
            const int nw = rows * K;
            const float4* s4 = reinterpret_cast<const float4*>(in + (size_t)base * K);
            const int nv = nw >> 2;
            for (int i = tid; i < nv; i += 256)
                reinterpret_cast<float4*>(xbuf)[i] = s4[i];
            for (int i = (nv << 2) + tid; i < nw; i += 256)
                xbuf[i] = in[(size_t)base * K + i];
        }
        __syncthreads();
        float acc[16];
#pragma unroll
        for (int j = 0; j < 16; ++j) acc[j] = bsum[c0 + j];
        {
            const float sv1 = (lane < rows) ? s1[base + lane] : 0.f;
#pragma unroll
            for (int j = 0; j < 16; ++j) acc[j] = fmaf(sv1, wv1[c0 + j], acc[j]);
        }
        if constexpr (HAS_S2) {
            const float sv2 = (lane < rows) ? s2[base + lane] : 0.f;
#pragma unroll
            for (int j = 0; j < 16; ++j) acc[j] = fmaf(sv2, wv2[c0 + j], acc[j]);
        }
        {
            const float* xr = xbuf + lane * K;
#pragma unroll 5
            for (int k = 0; k < K; ++k) {
                const float xk = xr[k];
                const float* wk = Wsum + k * 64 + c0;
#pragma unroll
                for (int j = 0; j < 16; ++j) acc[j] = fmaf(xk, wk[j], acc[j]);
            }
        }
#pragma unroll
        for (int j = 0; j < 16; ++j) hbuf[lane * 65 + c0 + j] = fmaxf(acc[j], 0.f);
        __syncthreads();
        float a2[NREL][16];
#pragma unroll
        for (int rel = 0; rel < NREL; ++rel)
#pragma unroll
            for (int j = 0; j < 16; ++j)
                a2[rel][j] = HAS_B2 ? b2v[rel * 64 + c0 + j] : 0.f;
        {
            const float* hr = hbuf + lane * 65;
#pragma unroll 4
            for (int k = 0; k < 64; ++k) {
                const float hk = hr[k];
#pragma unroll
                for (int rel = 0; rel < NREL; ++rel) {
                    const float* wk = W2 + rel * 4096 + k * 64 + c0;
#pragma unroll
                    for (int j = 0; j < 16; ++j)
                        a2[rel][j] = fmaf(hk, wk[j], a2[rel][j]);
                }
            }
        }
        if (lane < rows) {
            float* o0 = out0 + (size_t)(base + lane) * 64 + c0;
#pragma unroll
            for (int j4 = 0; j4 < 4; ++j4)
                reinterpret_cast<float4*>(o0)[j4] =
                    make_float4(a2[0][4*j4], a2[0][4*j4+1], a2[0][4*j4+2], a2[0][4*j4+3]);
            if constexpr (NREL == 2) {
                float* o1 = out1 + (size_t)(base + lane) * 64 + c0;
#pragma unroll
                for (int j4 = 0; j4 < 4; ++j4)
                    reinterpret_cast<float4*>(o1)[j4] =
                        make_float4(a2[1][4*j4], a2[1][4*j4+1], a2[1][4*j4+2], a2[1][4*j4+3]);
            }
        }
    }
}

// ---------------------------------------------------------------------------
__global__ __launch_bounds__(256)
void prep(const float* __restrict__ w1dt, const float* __restrict__ b1t,
          float* __restrict__ wsum, float* __restrict__ bsum)
{
    const int i = blockIdx.x * 256 + threadIdx.x;
    if (i < 85 * 64) wsum[i] = w1dt[i] + w1dt[85 * 64 + i];
    if (i < 64)      bsum[i] = b1t[i] + b1t[64 + i];
}

// ---------------------------------------------------------------------------
// CSR build over ONE concatenated key space:
//   [0,Nc): card (pays src)   payload dst_pays
//   [Nc,Nc+Nm): merchant (recv src)  payload dst_recv
//   [Nc+Nm,+Nt): transaction (pays dst)  payload src_pays
//   [Nc+Nm+Nt,+Nt): transaction (recv dst)  payload src_recv
// Each sub-histogram sums to E, so one global exclusive scan needs no carry
// fixups. After `fill`, off[i] holds the END of segment i (start = off[i-1]).
// ---------------------------------------------------------------------------
__global__ __launch_bounds__(256)
void hist(const int* __restrict__ sp, const int* __restrict__ dp,
          const int* __restrict__ sr, const int* __restrict__ dr,
          int E, int Nc, int Nm, int Nt, int* __restrict__ cnt)
{
    const int stride = gridDim.x * 256;
    for (int e = blockIdx.x * 256 + threadIdx.x; e < E; e += stride) {
        atomicAdd(&cnt[sp[e]], 1);
        atomicAdd(&cnt[Nc + sr[e]], 1);
        atomicAdd(&cnt[Nc + Nm + dp[e]], 1);
        atomicAdd(&cnt[Nc + Nm + Nt + dr[e]], 1);
    }
}

__global__ __launch_bounds__(256)
void scan_p1(const int* __restrict__ cnt, int n, int* __restrict__ part)
{
    __shared__ int sdata[256];
    const int b = blockIdx.x, t = threadIdx.x;
    const int base = b * 4096;
    int s = 0;
    for (int i = t; i < 4096; i += 256) {
        const int idx = base + i;
        s += (idx < n) ? cnt[idx] : 0;
    }
    sdata[t] = s; __syncthreads();
    for (int off = 128; off > 0; off >>= 1) {
        if (t < off) sdata[t] += sdata[t + off];
        __syncthreads();
    }
    if (t == 0) part[b] = sdata[0];
}

__global__ __launch_bounds__(256)
void scan_p2(int* __restrict__ part, int nb)
{
    __shared__ int sdata[256];
    const int t = threadIdx.x;
    int carry = 0;
    for (int base = 0; base < nb; base += 256) {
        const int idx = base + t;
        const int v = (idx < nb) ? part[idx] : 0;
        sdata[t] = v; __syncthreads();
        for (int off = 1; off < 256; off <<= 1) {
            const int x = (t >= off) ? sdata[t - off] : 0;
            __syncthreads();
            sdata[t] += x;
            __syncthreads();
        }
        const int incl  = sdata[t];
        const int total = sdata[255];
        if (idx < nb) part[idx] = carry + incl - v;   // exclusive
        carry += total;
        __syncthreads();
    }
}

__global__ __launch_bounds__(256)
void scan_p3(int* __restrict__ cnt, int n, const int* __restrict__ part)
{
    __shared__ int sums[256];
    const int b = blockIdx.x, t = threadIdx.x;
    const int base = b * 4096 + t * 16;
    int v[16];
    int s = 0;
#pragma unroll
    for (int j = 0; j < 16; ++j) {
        const int idx = base + j;
        v[j] = (idx < n) ? cnt[idx] : 0;
        s += v[j];
    }
    sums[t] = s; __syncthreads();
    for (int off = 1; off < 256; off <<= 1) {
        const int x = (t >= off) ? sums[t - off] : 0;
        __syncthreads();
        sums[t] += x;
        __syncthreads();
    }
    int run = part[b] + sums[t] - s;   // exclusive prefix at `base`
#pragma unroll
    for (int j = 0; j < 16; ++j) {
        const int idx = base + j;
        if (idx < n) cnt[idx] = run;
        run += v[j];
    }
}

__global__ __launch_bounds__(256)
void fill(const int* __restrict__ sp, const int* __restrict__ dp,
          const int* __restrict__ sr, const int* __restrict__ dr,
          int E, int Nc, int Nm, int Nt,
          int* __restrict__ off, int* __restrict__ adj)
{
    const int stride = gridDim.x * 256;
    for (int e = blockIdx.x * 256 + threadIdx.x; e < E; e += stride) {
        int p;
        p = atomicAdd(&off[sp[e]], 1);                adj[p] = dp[e];
        p = atomicAdd(&off[Nc + sr[e]], 1);           adj[p] = dr[e];
        p = atomicAdd(&off[Nc + Nm + dp[e]], 1);      adj[p] = sp[e];
        p = atomicAdd(&off[Nc + Nm + Nt + dr[e]], 1); adj[p] = sr[e];
    }
}

// ---------------------------------------------------------------------------
// gather_scalar: agg_c[t] = sum x_card[adjT0(t)], agg_m[t] = sum x_merch[adjT1(t)]
// ---------------------------------------------------------------------------
__global__ __launch_bounds__(256)
void gather_scalar(const float* __restrict__ x_card, const float* __restrict__ x_merch,
                   const int* __restrict__ off, const int* __restrict__ adj,
                   int Nc, int Nm, int Nt,
                   float* __restrict__ agg_c, float* __restrict__ agg_m)
{
    const int stride = gridDim.x * 256;
    const int b0 = Nc + Nm, b1 = Nc + Nm + Nt;
    for (int t = blockIdx.x * 256 + threadIdx.x; t < Nt; t += stride) {
        {
            const int i0 = b0 + t;
            float a = 0.f;
            for (int j = off[i0 - 1]; j < off[i0]; ++j) a += x_card[adj[j]];
            agg_c[t] = a;
        }
        {
            const int i1 = b1 + t;
            float a = 0.f;
            for (int j = off[i1 - 1]; j < off[i1]; ++j) a += x_merch[adj[j]];
            agg_m[t] = a;
        }
    }
}

// ---------------------------------------------------------------------------
// gather85: per card/merchant node, sum x_trans rows of its edge list.
// Wave per node; lane = channel (85 via two accumulators).
// ---------------------------------------------------------------------------
__global__ __launch_bounds__(256)
void gather85(const float* __restrict__ xt,
              const int* __restrict__ off, const int* __restrict__ adj,
              int Nc, int Nm,
              float* __restrict__ aggC, float* __restrict__ aggM)
{
    const int lane = threadIdx.x & 63;
    const int gw   = blockIdx.x * (blockDim.x >> 6) + (threadIdx.x >> 6);
    const int nw   = gridDim.x * (blockDim.x >> 6);
    const int N = Nc + Nm;
    for (int i = gw; i < N; i += nw) {
        const int s = (i == 0) ? 0 : off[i - 1];
        const int e = off[i];
        float a0 = 0.f, a1 = 0.f;
        for (int j = s; j < e; ++j) {
            const float* xr = xt + (size_t)adj[j] * 85;
            a0 += xr[lane];
            if (lane < 21) a1 += xr[64 + lane];
        }
        float* dst = (i < Nc) ? aggC + (size_t)i * 85 : aggM + (size_t)(i - Nc) * 85;
        dst[lane] = a0;
        if (lane < 21) dst[64 + lane] = a1;
    }
}

// ---------------------------------------------------------------------------
// gather_final: per transaction t (wave per t):
//   v0 = tacc0[t] + sum z1[adjT0(t)];  v1 = tacc1[t] + sum z2[adjT1(t)]
//   out[t] = relu(v0)@wl[0:64] + relu(v1)@wl[64:128] + bl
// ---------------------------------------------------------------------------
__global__ __launch_bounds__(256)
void gather_final(const float* __restrict__ tacc0, const float* __restrict__ tacc1,
                  const float* __restrict__ z1, const float* __restrict__ z2,
                  const int* __restrict__ off, const int* __restrict__ adj,
                  int Nc, int Nm, int Nt,
                  const float* __restrict__ wl, const float* __restrict__ bl,
                  float* __restrict__ out)
{
    const int lane = threadIdx.x & 63;
    const int gw   = blockIdx.x * (blockDim.x >> 6) + (threadIdx.x >> 6);
    const int nw   = gridDim.x * (blockDim.x >> 6);
    const float w0a = wl[lane * 2 + 0],        w0b = wl[lane * 2 + 1];
    const float w1a = wl[(64 + lane) * 2 + 0], w1b = wl[(64 + lane) * 2 + 1];
    const float b0 = bl[0], b1 = bl[1];
    const int base0 = Nc + Nm, base1 = Nc + Nm + Nt;
    for (int t = gw; t < Nt; t += nw) {
        float v0 = tacc0[(size_t)t * 64 + lane];
        {
            const int i0 = base0 + t;
            for (int j = off[i0 - 1]; j < off[i0]; ++j)
                v0 += z1[(size_t)adj[j] * 64 + lane];
        }
        float v1 = tacc1[(size_t)t * 64 + lane];
        {
            const int i1 = base1 + t;
            for (int j = off[i1 - 1]; j < off[i1]; ++j)
                v1 += z2[(size_t)adj[j] * 64 + lane];
        }
        v0 = fmaxf(v0, 0.f);
        v1 = fmaxf(v1, 0.f);
        float a = v0 * w0a + v1 * w1a;
        float b = v0 * w0b + v1 * w1b;
#pragma unroll
        for (int o = 32; o > 0; o >>= 1) {
            a += __shfl_xor(a, o);
            b += __shfl_xor(b, o);
        }
        if (lane == 0) {
            out[(size_t)t * 2 + 0] = a + b0;
            out[(size_t)t * 2 + 1] = b + b1;
        }
    }
}

// ---------------------------------------------------------------------------
extern "C" void kernel_launch(void* const* d_in, const int* in_sizes, int n_in,
                              void* d_out, int out_size, void* d_ws, size_t ws_size,
                              hipStream_t stream)
{
    const float* x_card   = (const float*)d_in[0];
    const float* x_merch  = (const float*)d_in[1];
    const float* x_trans  = (const float*)d_in[2];
    const float* w1_src_t = (const float*)d_in[3];   // [2,1,64]
    const float* w1_dst_t = (const float*)d_in[4];   // [2,85,64]
    const float* b1_t     = (const float*)d_in[5];   // [2,64]
    const float* w1_src_r = (const float*)d_in[6];   // [2,85,64]
    const float* w1_dst_r = (const float*)d_in[7];   // [2,1,64]
    const float* b1_r     = (const float*)d_in[8];   // [2,64]
    const float* w2_l     = (const float*)d_in[9];   // [4,64,64]
    const float* w2_r     = (const float*)d_in[10];  // [4,64,64]
    const float* b2       = (const float*)d_in[11];  // [4,64]
    const float* w_lin    = (const float*)d_in[12];  // [128,2]
    const float* b_lin    = (const float*)d_in[13];  // [2]
    const int*   src_pays = (const int*)d_in[14];
    const int*   dst_pays = (const int*)d_in[15];
    const int*   src_recv = (const int*)d_in[16];
    const int*   dst_recv = (const int*)d_in[17];
    float*       out      = (float*)d_out;

    const int Nc = in_sizes[0];
    const int Nm = in_sizes[1];
    const int Nt = in_sizes[2] / 85;
    const int E  = in_sizes[14];
    const int Ntot = Nc + Nm + 2 * Nt;
    const int NB   = (Ntot + 4095) / 4096;

    // workspace layout
    char* wsp = (char*)d_ws;
    auto alloc = [&](size_t bytes) -> void* {
        char* p = wsp;
        wsp += (bytes + 255) & ~(size_t)255;
        return (void*)p;
    };
    int*   cnt    = (int*)alloc((size_t)Ntot * 4);       // -> off (scan) -> end-off (fill)
    const size_t zero_bytes = (size_t)(wsp - (char*)d_ws);
    int*   part   = (int*)alloc((size_t)(NB + 1) * 4);
    int*   adj    = (int*)alloc((size_t)4 * E * 4);
    float* agg_c  = (float*)alloc((size_t)Nt * 4);
    float* agg_m  = (float*)alloc((size_t)Nt * 4);
    float* aggT_c = (float*)alloc((size_t)Nc * 85 * 4);
    float* aggT_m = (float*)alloc((size_t)Nm * 85 * 4);
    float* wsum   = (float*)alloc((size_t)85 * 64 * 4);
    float* bsum   = (float*)alloc((size_t)64 * 4);
    float* z1     = (float*)alloc((size_t)Nc * 64 * 4);
    float* z2     = (float*)alloc((size_t)Nm * 64 * 4);
    float* tacc0  = (float*)alloc((size_t)Nt * 64 * 4);
    float* tacc1  = (float*)alloc((size_t)Nt * 64 * 4);
    (void)ws_size; (void)n_in; (void)out_size;

    hipMemsetAsync(d_ws, 0, zero_bytes, stream);   // zero cnt only

    const dim3 blk(256);
    const int gE = MIN((E + 255) / 256, 2048);
    auto tiles = [](int M) { return (M + 63) / 64; };

    // weight precompute
    prep<<<(85 * 64 + 255) / 256, blk, 0, stream>>>(w1_dst_t, b1_t, wsum, bsum);

    // ---- CSR build ----
    hist<<<gE, blk, 0, stream>>>(src_pays, dst_pays, src_recv, dst_recv, E, Nc, Nm, Nt, cnt);
    scan_p1<<<NB, blk, 0, stream>>>(cnt, Ntot, part);
    scan_p2<<<1, blk, 0, stream>>>(part, NB);
    scan_p3<<<NB, blk, 0, stream>>>(cnt, Ntot, part);
    fill<<<gE, blk, 0, stream>>>(src_pays, dst_pays, src_recv, dst_recv, E, Nc, Nm, Nt, cnt, adj);

    // ---- conv1 aggregations (pure gathers) ----
    gather_scalar<<<MIN((Nt + 255) / 256, 2048), blk, 0, stream>>>(
        x_card, x_merch, cnt, adj, Nc, Nm, Nt, agg_c, agg_m);
    gather85<<<2048, blk, 0, stream>>>(x_trans, cnt, adj, Nc, Nm, aggT_c, aggT_m);

    // ---- fused dense pipelines ----
    fused_sage85<2, true, true><<<tiles(Nt), blk, 0, stream>>>(
        x_trans, Nt, wsum, bsum,
        agg_c, w1_src_t, agg_m, w1_src_t + 64,
        w2_r, b2, tacc0, tacc1);
    fused_sage85<1, false, false><<<tiles(Nc), blk, 0, stream>>>(
        aggT_c, Nc, w1_src_r, b1_r,
        x_card, w1_dst_r, nullptr, nullptr,
        w2_l, nullptr, z1, nullptr);
    fused_sage85<1, false, false><<<tiles(Nm), blk, 0, stream>>>(
        aggT_m, Nm, w1_src_r + 85 * 64, b1_r + 64,
        x_merch, w1_dst_r + 64, nullptr, nullptr,
        w2_l + 64 * 64, nullptr, z2, nullptr);

    // ---- conv2 neighbor gather + final projection, fused ----
    gather_final<<<2048, blk, 0, stream>>>(
        tacc0, tacc1, z1, z2, cnt, adj, Nc, Nm, Nt, w_lin, b_lin, out);
}

// Round 5
// 664.665 us; speedup vs baseline: 4.4718x; 1.4264x over previous
//
#include <hip/hip_runtime.h>
#include <hip/hip_bf16.h>

#ifndef MIN
#define MIN(a,b) ((a)<(b)?(a):(b))
#endif

#define RFL(x) __builtin_amdgcn_readfirstlane(x)

// ---------------------------------------------------------------------------
// fused_small: per 64-row tile of `in` [M][85]:
//   h[r][c] = relu( in[r,:]@Wsum[:,c] + bsum[c] + s1[r]*wv1[c] )
//   out0[r][c] = h[r,:]@W2[:,c]
// h is aliased into xbuf (pitch 85) after phase-1 reads complete -> 22KB LDS.
// ---------------------------------------------------------------------------
__global__ __launch_bounds__(256, 7)
void fused_small(const float* __restrict__ in, int M,
                 const float* __restrict__ Wsum,   // [85][64]
                 const float* __restrict__ bsum,   // [64]
                 const float* __restrict__ s1, const float* __restrict__ wv1,
                 const float* __restrict__ W2,     // [64][64]
                 float* __restrict__ out0)
{
    constexpr int K = 85;
    __shared__ float xbuf[64 * K];
    const int tid  = threadIdx.x;
    const int lane = tid & 63;
    const int wid  = tid >> 6;
    const int c0   = RFL(wid * 16);

    const int ntiles = (M + 63) >> 6;
    for (int t = blockIdx.x; t < ntiles; t += gridDim.x) {
        const int base = t << 6;
        const int rows = MIN(64, M - base);
        __syncthreads();
        {
            const int nw = rows * K;
            const float4* s4 = reinterpret_cast<const float4*>(in + (size_t)base * K);
            const int nv = nw >> 2;
            for (int i = tid; i < nv; i += 256)
                reinterpret_cast<float4*>(xbuf)[i] = s4[i];
            for (int i = (nv << 2) + tid; i < nw; i += 256)
                xbuf[i] = in[(size_t)base * K + i];
        }
        __syncthreads();
        // phase 1
        float acc[16];
#pragma unroll
        for (int j = 0; j < 16; ++j) acc[j] = bsum[c0 + j];
        {
            const float sv1 = (lane < rows) ? s1[base + lane] : 0.f;
#pragma unroll
            for (int j = 0; j < 16; ++j) acc[j] = fmaf(sv1, wv1[c0 + j], acc[j]);
        }
        {
            const float* xr = xbuf + lane * K;
#pragma unroll 5
            for (int k = 0; k < K; ++k) {
                const float xk = xr[k];
                const float* wk = Wsum + k * 64 + c0;
#pragma unroll
                for (int j = 0; j < 16; ++j) acc[j] = fmaf(xk, wk[j], acc[j]);
            }
        }
        __syncthreads();          // all phase-1 xbuf reads done
#pragma unroll
        for (int j = 0; j < 16; ++j) xbuf[lane * K + c0 + j] = fmaxf(acc[j], 0.f);
        __syncthreads();
        // phase 2
        float a2[16];
#pragma unroll
        for (int j = 0; j < 16; ++j) a2[j] = 0.f;
        {
            const float* hr = xbuf + lane * K;
#pragma unroll 4
            for (int k = 0; k < 64; ++k) {
                const float hk = hr[k];
                const float* wk = W2 + k * 64 + c0;
#pragma unroll
                for (int j = 0; j < 16; ++j) a2[j] = fmaf(hk, wk[j], a2[j]);
            }
        }
        if (lane < rows) {
            float* o0 = out0 + (size_t)(base + lane) * 64 + c0;
#pragma unroll
            for (int j4 = 0; j4 < 4; ++j4)
                reinterpret_cast<float4*>(o0)[j4] =
                    make_float4(a2[4*j4], a2[4*j4+1], a2[4*j4+2], a2[4*j4+3]);
        }
    }
}

// ---------------------------------------------------------------------------
// mega_tf: per 64-row tile of transactions:
//   h[r][c]  = relu( x[r,:]@Wsum[:,c] + bsum[c] + s1[r]*wv1[c] + s2[r]*wv2[c] )
//   vR[r][c] = h[r,:]@W2[R][:,c] + b2v[R][c] + sum_{e in adjR(r)} zR[e][c]
//   out[r][o] = bl[o] + sum_c relu(v0[r][c])*wl[c][o] + relu(v1[r][c])*wl[64+c][o]
// Cross-wave column reduction via LDS atomicAdd into obuf[64][2].
// ---------------------------------------------------------------------------
__global__ __launch_bounds__(256, 6)
void mega_tf(const float* __restrict__ in, int M,
             const float* __restrict__ Wsum,   // [85][64]
             const float* __restrict__ bsum,   // [64]
             const float* __restrict__ s1, const float* __restrict__ wv1,
             const float* __restrict__ s2, const float* __restrict__ wv2,
             const float* __restrict__ W2,     // [2][64][64] (w2_r)
             const float* __restrict__ b2v,    // [2][64]
             const float* __restrict__ z1, const float* __restrict__ z2,
             const int* __restrict__ off, const int* __restrict__ adj,
             int zb0, int zb1,                 // segment bases: Nc+Nm, Nc+Nm+Nt
             const float* __restrict__ wl, const float* __restrict__ bl,
             float* __restrict__ out)
{
    constexpr int K = 85;
    __shared__ float xbuf[64 * K];
    __shared__ float obuf[64][2];
    const int tid  = threadIdx.x;
    const int lane = tid & 63;
    const int wid  = tid >> 6;
    const int c0   = RFL(wid * 16);

    const int ntiles = (M + 63) >> 6;
    for (int t = blockIdx.x; t < ntiles; t += gridDim.x) {
        const int base = t << 6;
        const int rows = MIN(64, M - base);
        __syncthreads();
        {
            const int nw = rows * K;
            const float4* s4 = reinterpret_cast<const float4*>(in + (size_t)base * K);
            const int nv = nw >> 2;
            for (int i = tid; i < nv; i += 256)
                reinterpret_cast<float4*>(xbuf)[i] = s4[i];
            for (int i = (nv << 2) + tid; i < nw; i += 256)
                xbuf[i] = in[(size_t)base * K + i];
        }
        if (tid < 128) ((float*)obuf)[tid] = 0.f;
        __syncthreads();
        // ---- phase 1 ----
        float acc[16];
#pragma unroll
        for (int j = 0; j < 16; ++j) acc[j] = bsum[c0 + j];
        {
            const float sv1 = (lane < rows) ? s1[base + lane] : 0.f;
#pragma unroll
            for (int j = 0; j < 16; ++j) acc[j] = fmaf(sv1, wv1[c0 + j], acc[j]);
        }
        {
            const float sv2 = (lane < rows) ? s2[base + lane] : 0.f;
#pragma unroll
            for (int j = 0; j < 16; ++j) acc[j] = fmaf(sv2, wv2[c0 + j], acc[j]);
        }
        {
            const float* xr = xbuf + lane * K;
#pragma unroll 5
            for (int k = 0; k < K; ++k) {
                const float xk = xr[k];
                const float* wk = Wsum + k * 64 + c0;
#pragma unroll
                for (int j = 0; j < 16; ++j) acc[j] = fmaf(xk, wk[j], acc[j]);
            }
        }
        __syncthreads();          // all phase-1 xbuf reads done
#pragma unroll
        for (int j = 0; j < 16; ++j) xbuf[lane * K + c0 + j] = fmaxf(acc[j], 0.f);
        __syncthreads();
        // ---- phase 2: v0, v1 ----
        float a0[16], a1[16];
#pragma unroll
        for (int j = 0; j < 16; ++j) {
            a0[j] = b2v[c0 + j];
            a1[j] = b2v[64 + c0 + j];
        }
        {
            const float* hr = xbuf + lane * K;
#pragma unroll 4
            for (int k = 0; k < 64; ++k) {
                const float hk = hr[k];
                const float* wk0 = W2 + k * 64 + c0;
                const float* wk1 = W2 + 4096 + k * 64 + c0;
#pragma unroll
                for (int j = 0; j < 16; ++j) {
                    a0[j] = fmaf(hk, wk0[j], a0[j]);
                    a1[j] = fmaf(hk, wk1[j], a1[j]);
                }
            }
        }
        // ---- z gathers (per-lane edge lists, avg degree ~1) ----
        if (lane < rows) {
            {
                const int i0 = zb0 + base + lane;
                const int e0 = off[i0 - 1], e1 = off[i0];
                for (int j = e0; j < e1; ++j) {
                    const float4* zr = reinterpret_cast<const float4*>(
                        z1 + (size_t)adj[j] * 64 + c0);
#pragma unroll
                    for (int q = 0; q < 4; ++q) {
                        const float4 v = zr[q];
                        a0[4*q+0] += v.x; a0[4*q+1] += v.y;
                        a0[4*q+2] += v.z; a0[4*q+3] += v.w;
                    }
                }
            }
            {
                const int i1 = zb1 + base + lane;
                const int e0 = off[i1 - 1], e1 = off[i1];
                for (int j = e0; j < e1; ++j) {
                    const float4* zr = reinterpret_cast<const float4*>(
                        z2 + (size_t)adj[j] * 64 + c0);
#pragma unroll
                    for (int q = 0; q < 4; ++q) {
                        const float4 v = zr[q];
                        a1[4*q+0] += v.x; a1[4*q+1] += v.y;
                        a1[4*q+2] += v.z; a1[4*q+3] += v.w;
                    }
                }
            }
        }
        // ---- relu + partial projection for this wave's 16 columns ----
        float pa = 0.f, pb = 0.f;
#pragma unroll
        for (int j = 0; j < 16; ++j) {
            const int c = c0 + j;
            const float v0 = fmaxf(a0[j], 0.f);
            const float v1 = fmaxf(a1[j], 0.f);
            pa += v0 * wl[c * 2 + 0] + v1 * wl[(64 + c) * 2 + 0];
            pb += v0 * wl[c * 2 + 1] + v1 * wl[(64 + c) * 2 + 1];
        }
        atomicAdd(&obuf[lane][0], pa);
        atomicAdd(&obuf[lane][1], pb);
        __syncthreads();
        if (tid < 2 * rows) {
            const int r = tid >> 1, o = tid & 1;
            out[(size_t)(base + r) * 2 + o] = obuf[r][o] + bl[o];
        }
    }
}

// ---------------------------------------------------------------------------
__global__ __launch_bounds__(256)
void prep(const float* __restrict__ w1dt, const float* __restrict__ b1t,
          float* __restrict__ wsum, float* __restrict__ bsum)
{
    const int i = blockIdx.x * 256 + threadIdx.x;
    if (i < 85 * 64) wsum[i] = w1dt[i] + w1dt[85 * 64 + i];
    if (i < 64)      bsum[i] = b1t[i] + b1t[64 + i];
}

// ---------------------------------------------------------------------------
// CSR build over ONE concatenated key space (see R4 comments).
// ---------------------------------------------------------------------------
__global__ __launch_bounds__(256)
void hist(const int* __restrict__ sp, const int* __restrict__ dp,
          const int* __restrict__ sr, const int* __restrict__ dr,
          int E, int Nc, int Nm, int Nt, int* __restrict__ cnt)
{
    const int stride = gridDim.x * 256;
    for (int e = blockIdx.x * 256 + threadIdx.x; e < E; e += stride) {
        atomicAdd(&cnt[sp[e]], 1);
        atomicAdd(&cnt[Nc + sr[e]], 1);
        atomicAdd(&cnt[Nc + Nm + dp[e]], 1);
        atomicAdd(&cnt[Nc + Nm + Nt + dr[e]], 1);
    }
}

__global__ __launch_bounds__(256)
void scan_p1(const int* __restrict__ cnt, int n, int* __restrict__ part)
{
    __shared__ int sdata[256];
    const int b = blockIdx.x, t = threadIdx.x;
    const int base = b * 4096;
    int s = 0;
    for (int i = t; i < 4096; i += 256) {
        const int idx = base + i;
        s += (idx < n) ? cnt[idx] : 0;
    }
    sdata[t] = s; __syncthreads();
    for (int off = 128; off > 0; off >>= 1) {
        if (t < off) sdata[t] += sdata[t + off];
        __syncthreads();
    }
    if (t == 0) part[b] = sdata[0];
}

__global__ __launch_bounds__(256)
void scan_p2(int* __restrict__ part, int nb)
{
    __shared__ int sdata[256];
    const int t = threadIdx.x;
    int carry = 0;
    for (int base = 0; base < nb; base += 256) {
        const int idx = base + t;
        const int v = (idx < nb) ? part[idx] : 0;
        sdata[t] = v; __syncthreads();
        for (int off = 1; off < 256; off <<= 1) {
            const int x = (t >= off) ? sdata[t - off] : 0;
            __syncthreads();
            sdata[t] += x;
            __syncthreads();
        }
        const int incl  = sdata[t];
        const int total = sdata[255];
        if (idx < nb) part[idx] = carry + incl - v;
        carry += total;
        __syncthreads();
    }
}

__global__ __launch_bounds__(256)
void scan_p3(int* __restrict__ cnt, int n, const int* __restrict__ part)
{
    __shared__ int sums[256];
    const int b = blockIdx.x, t = threadIdx.x;
    const int base = b * 4096 + t * 16;
    int v[16];
    int s = 0;
#pragma unroll
    for (int j = 0; j < 16; ++j) {
        const int idx = base + j;
        v[j] = (idx < n) ? cnt[idx] : 0;
        s += v[j];
    }
    sums[t] = s; __syncthreads();
    for (int off = 1; off < 256; off <<= 1) {
        const int x = (t >= off) ? sums[t - off] : 0;
        __syncthreads();
        sums[t] += x;
        __syncthreads();
    }
    int run = part[b] + sums[t] - s;
#pragma unroll
    for (int j = 0; j < 16; ++j) {
        const int idx = base + j;
        if (idx < n) cnt[idx] = run;
        run += v[j];
    }
}

__global__ __launch_bounds__(256)
void fill(const int* __restrict__ sp, const int* __restrict__ dp,
          const int* __restrict__ sr, const int* __restrict__ dr,
          int E, int Nc, int Nm, int Nt,
          int* __restrict__ off, int* __restrict__ adj)
{
    const int stride = gridDim.x * 256;
    for (int e = blockIdx.x * 256 + threadIdx.x; e < E; e += stride) {
        int p;
        p = atomicAdd(&off[sp[e]], 1);                adj[p] = dp[e];
        p = atomicAdd(&off[Nc + sr[e]], 1);           adj[p] = dr[e];
        p = atomicAdd(&off[Nc + Nm + dp[e]], 1);      adj[p] = sp[e];
        p = atomicAdd(&off[Nc + Nm + Nt + dr[e]], 1); adj[p] = sr[e];
    }
}

// ---------------------------------------------------------------------------
__global__ __launch_bounds__(256)
void gather_scalar(const float* __restrict__ x_card, const float* __restrict__ x_merch,
                   const int* __restrict__ off, const int* __restrict__ adj,
                   int Nc, int Nm, int Nt,
                   float* __restrict__ agg_c, float* __restrict__ agg_m)
{
    const int stride = gridDim.x * 256;
    const int b0 = Nc + Nm, b1 = Nc + Nm + Nt;
    for (int t = blockIdx.x * 256 + threadIdx.x; t < Nt; t += stride) {
        {
            const int i0 = b0 + t;
            float a = 0.f;
            for (int j = off[i0 - 1]; j < off[i0]; ++j) a += x_card[adj[j]];
            agg_c[t] = a;
        }
        {
            const int i1 = b1 + t;
            float a = 0.f;
            for (int j = off[i1 - 1]; j < off[i1]; ++j) a += x_merch[adj[j]];
            agg_m[t] = a;
        }
    }
}

// ---------------------------------------------------------------------------
__global__ __launch_bounds__(256)
void gather85(const float* __restrict__ xt,
              const int* __restrict__ off, const int* __restrict__ adj,
              int Nc, int Nm,
              float* __restrict__ aggC, float* __restrict__ aggM)
{
    const int lane = threadIdx.x & 63;
    const int gw   = blockIdx.x * (blockDim.x >> 6) + (threadIdx.x >> 6);
    const int nw   = gridDim.x * (blockDim.x >> 6);
    const int N = Nc + Nm;
    for (int i = gw; i < N; i += nw) {
        const int s = (i == 0) ? 0 : off[i - 1];
        const int e = off[i];
        float a0 = 0.f, a1 = 0.f;
        for (int j = s; j < e; ++j) {
            const float* xr = xt + (size_t)adj[j] * 85;
            a0 += xr[lane];
            if (lane < 21) a1 += xr[64 + lane];
        }
        float* dst = (i < Nc) ? aggC + (size_t)i * 85 : aggM + (size_t)(i - Nc) * 85;
        dst[lane] = a0;
        if (lane < 21) dst[64 + lane] = a1;
    }
}

// ---------------------------------------------------------------------------
extern "C" void kernel_launch(void* const* d_in, const int* in_sizes, int n_in,
                              void* d_out, int out_size, void* d_ws, size_t ws_size,
                              hipStream_t stream)
{
    const float* x_card   = (const float*)d_in[0];
    const float* x_merch  = (const float*)d_in[1];
    const float* x_trans  = (const float*)d_in[2];
    const float* w1_src_t = (const float*)d_in[3];   // [2,1,64]
    const float* w1_dst_t = (const float*)d_in[4];   // [2,85,64]
    const float* b1_t     = (const float*)d_in[5];   // [2,64]
    const float* w1_src_r = (const float*)d_in[6];   // [2,85,64]
    const float* w1_dst_r = (const float*)d_in[7];   // [2,1,64]
    const float* b1_r     = (const float*)d_in[8];   // [2,64]
    const float* w2_l     = (const float*)d_in[9];   // [4,64,64]
    const float* w2_r     = (const float*)d_in[10];  // [4,64,64]
    const float* b2       = (const float*)d_in[11];  // [4,64]
    const float* w_lin    = (const float*)d_in[12];  // [128,2]
    const float* b_lin    = (const float*)d_in[13];  // [2]
    const int*   src_pays = (const int*)d_in[14];
    const int*   dst_pays = (const int*)d_in[15];
    const int*   src_recv = (const int*)d_in[16];
    const int*   dst_recv = (const int*)d_in[17];
    float*       out      = (float*)d_out;

    const int Nc = in_sizes[0];
    const int Nm = in_sizes[1];
    const int Nt = in_sizes[2] / 85;
    const int E  = in_sizes[14];
    const int Ntot = Nc + Nm + 2 * Nt;
    const int NB   = (Ntot + 4095) / 4096;

    // workspace layout
    char* wsp = (char*)d_ws;
    auto alloc = [&](size_t bytes) -> void* {
        char* p = wsp;
        wsp += (bytes + 255) & ~(size_t)255;
        return (void*)p;
    };
    int*   cnt    = (int*)alloc((size_t)Ntot * 4);       // -> off after scan/fill
    const size_t zero_bytes = (size_t)(wsp - (char*)d_ws);
    int*   part   = (int*)alloc((size_t)(NB + 1) * 4);
    int*   adj    = (int*)alloc((size_t)4 * E * 4);
    float* agg_c  = (float*)alloc((size_t)Nt * 4);
    float* agg_m  = (float*)alloc((size_t)Nt * 4);
    float* aggT_c = (float*)alloc((size_t)Nc * 85 * 4);
    float* aggT_m = (float*)alloc((size_t)Nm * 85 * 4);
    float* wsum   = (float*)alloc((size_t)85 * 64 * 4);
    float* bsum   = (float*)alloc((size_t)64 * 4);
    float* z1     = (float*)alloc((size_t)Nc * 64 * 4);
    float* z2     = (float*)alloc((size_t)Nm * 64 * 4);
    (void)ws_size; (void)n_in; (void)out_size;

    hipMemsetAsync(d_ws, 0, zero_bytes, stream);   // zero cnt only

    const dim3 blk(256);
    const int gE = MIN((E + 255) / 256, 2048);
    auto tiles = [](int M) { return (M + 63) / 64; };

    // weight precompute
    prep<<<(85 * 64 + 255) / 256, blk, 0, stream>>>(w1_dst_t, b1_t, wsum, bsum);

    // ---- CSR build ----
    hist<<<gE, blk, 0, stream>>>(src_pays, dst_pays, src_recv, dst_recv, E, Nc, Nm, Nt, cnt);
    scan_p1<<<NB, blk, 0, stream>>>(cnt, Ntot, part);
    scan_p2<<<1, blk, 0, stream>>>(part, NB);
    scan_p3<<<NB, blk, 0, stream>>>(cnt, Ntot, part);
    fill<<<gE, blk, 0, stream>>>(src_pays, dst_pays, src_recv, dst_recv, E, Nc, Nm, Nt, cnt, adj);

    // ---- conv1 aggregations (pure gathers) ----
    gather_scalar<<<MIN((Nt + 255) / 256, 2048), blk, 0, stream>>>(
        x_card, x_merch, cnt, adj, Nc, Nm, Nt, agg_c, agg_m);
    gather85<<<2048, blk, 0, stream>>>(x_trans, cnt, adj, Nc, Nm, aggT_c, aggT_m);

    // ---- small fused pipelines: aggT -> h -> z ----
    fused_small<<<tiles(Nc), blk, 0, stream>>>(
        aggT_c, Nc, w1_src_r, b1_r, x_card, w1_dst_r, w2_l, z1);
    fused_small<<<tiles(Nm), blk, 0, stream>>>(
        aggT_m, Nm, w1_src_r + 85 * 64, b1_r + 64, x_merch, w1_dst_r + 64,
        w2_l + 64 * 64, z2);

    // ---- megakernel: x_trans -> h_t -> v0,v1 (+z gather) -> out ----
    mega_tf<<<tiles(Nt), blk, 0, stream>>>(
        x_trans, Nt, wsum, bsum,
        agg_c, w1_src_t, agg_m, w1_src_t + 64,
        w2_r, b2, z1, z2,
        cnt, adj, Nc + Nm, Nc + Nm + Nt,
        w_lin, b_lin, out);
}